// Round 1
// baseline (367.460 us; speedup 1.0000x reference)
//
#include <hip/hip_runtime.h>
#include <math.h>

#define NDIM 512
#define NROWS 256  // B*S = 2*128

__global__ __launch_bounds__(256) void gs_gemm(const float* __restrict__ x,
                                               const float* __restrict__ W,
                                               const float* __restrict__ b,
                                               const float* __restrict__ eps,
                                               float* __restrict__ out) {
    __shared__ float xs[NDIM];
    const int r = blockIdx.x;
    const int tid = threadIdx.x;

    // Stage x row into LDS (coalesced global load, broadcast reuse later)
    const float* xrow = x + (size_t)r * NDIM;
    xs[tid] = xrow[tid];
    xs[tid + 256] = xrow[tid + 256];
    __syncthreads();

    float* out_sample = out;                                   // 256*512 floats
    float* out_mu     = out + (size_t)NROWS * NDIM;            // next 256*512
    float* out_std    = out + (size_t)2 * NROWS * NDIM;        // 256*512*512

    const float4* xs4 = (const float4*)xs;

    // Each thread handles columns ii = tid and tid+256.
    // For each ii: stats[m=ii] -> var path, stats[m=ii+512] -> mu path.
    for (int ii = tid; ii < NDIM; ii += 256) {
        const float4* wa = (const float4*)(W + (size_t)ii * NDIM);          // softplus half
        const float4* wb = (const float4*)(W + (size_t)(ii + NDIM) * NDIM); // mu half
        float s0 = 0.f, s1 = 0.f;
        #pragma unroll 8
        for (int k = 0; k < NDIM / 4; ++k) {
            float4 xv = xs4[k];   // LDS broadcast (same addr across lanes)
            float4 a  = wa[k];
            float4 c  = wb[k];
            s0 += xv.x * a.x + xv.y * a.y + xv.z * a.z + xv.w * a.w;
            s1 += xv.x * c.x + xv.y * c.y + xv.z * c.z + xv.w * c.w;
        }
        s0 += b[ii];
        s1 += b[ii + NDIM];

        // softplus(s0) = log1p(exp(s0)), stable for large s0
        float var = (s0 > 20.f) ? s0 : log1pf(expf(s0));
        float mu  = s1;
        float smp = mu + sqrtf(var) * eps[(size_t)r * NDIM + ii];

        out_sample[(size_t)r * NDIM + ii] = smp;
        out_mu[(size_t)r * NDIM + ii]     = mu;
        // diagonal of std_mat (rest was zeroed by the memset before this kernel)
        out_std[(size_t)r * NDIM * NDIM + (size_t)ii * NDIM + ii] = var;
    }
}

extern "C" void kernel_launch(void* const* d_in, const int* in_sizes, int n_in,
                              void* d_out, int out_size, void* d_ws, size_t ws_size,
                              hipStream_t stream) {
    const float* x   = (const float*)d_in[0];
    const float* W   = (const float*)d_in[1];
    const float* b   = (const float*)d_in[2];
    const float* eps = (const float*)d_in[3];
    float* out = (float*)d_out;

    // Zero the std_mat region (256 MB). Stream-ordered: diagonal writes in the
    // kernel below are ordered after this memset.
    const size_t std_off_floats = (size_t)2 * NROWS * NDIM;           // sample + mu
    const size_t std_bytes      = (size_t)NROWS * NDIM * NDIM * sizeof(float);
    hipMemsetAsync(out + std_off_floats, 0, std_bytes, stream);

    gs_gemm<<<NROWS, 256, 0, stream>>>(x, W, b, eps, out);
}